// Round 1
// baseline (303.874 us; speedup 1.0000x reference)
//
#include <hip/hip_runtime.h>
#include <hip/hip_bf16.h>

#define E_EDGES 262144
#define DFEAT 256
#define KDIM 512

typedef __attribute__((ext_vector_type(8))) short short8;
typedef __attribute__((ext_vector_type(4))) float f32x4;

__device__ __forceinline__ unsigned short f2bf(float x) {
    unsigned u = __float_as_uint(x);
    u += 0x7fffu + ((u >> 16) & 1u);   // RNE
    return (unsigned short)(u >> 16);
}

// W1 [512][256] f32 -> W1T [256][512] bf16
__global__ __launch_bounds__(256) void prep_w1t_kernel(const float* __restrict__ W1,
                                                       unsigned short* __restrict__ w1t) {
    int idx = blockIdx.x * 256 + threadIdx.x;   // 131072 total
    int k = idx >> 8;
    int n = idx & 255;
    w1t[n * KDIM + k] = f2bf(W1[idx]);
}

__global__ __launch_bounds__(256) void linkpred_kernel(
    const float* __restrict__ table,
    const int* __restrict__ pos_src, const int* __restrict__ pos_dst,
    const int* __restrict__ neg_src, const int* __restrict__ neg_dst,
    const float* __restrict__ b1, const float* __restrict__ W2,
    const float* __restrict__ b2,
    const unsigned short* __restrict__ w1t,
    float* __restrict__ out) {

    __shared__ __align__(16) unsigned short As[2][64 * 64];  // 2 x 8 KB, XOR-swizzled rows
    __shared__ int sIdx[64], dIdx[64];
    __shared__ float wpart[4][64];

    const int tid = threadIdx.x;
    const int l = tid & 63;
    const int wv = tid >> 6;            // wave 0..3 -> HID cols [wv*64, wv*64+64)
    const int m0 = blockIdx.x * 64;     // 64 edges per block

    if (tid < 64) {
        int m = m0 + tid;
        int si, di;
        if (m < E_EDGES) { si = pos_src[m];            di = pos_dst[m]; }
        else             { si = neg_src[m - E_EDGES];  di = neg_dst[m - E_EDGES]; }
        sIdx[tid] = si;
        dIdx[tid] = di;
    }

    float b1v[4], w2v[4];
#pragma unroll
    for (int j = 0; j < 4; j++) {
        int n = wv * 64 + j * 16 + (l & 15);
        b1v[j] = b1[n];
        w2v[j] = W2[n];
    }

    __syncthreads();

    // staging decomposition: 256 threads cover 64 rows x 64 cols (8 bf16 per thread)
    const int e0 = tid >> 3;       // rows 0..31
    const int q  = tid & 7;        // 8-float column chunk
    const int e1 = e0 + 32;        // rows 32..63

    auto pack_write = [&](int buf, int e, const float4& x, const float4& y) {
        uint4 w;
        w.x = (unsigned)f2bf(x.x) | ((unsigned)f2bf(x.y) << 16);
        w.y = (unsigned)f2bf(x.z) | ((unsigned)f2bf(x.w) << 16);
        w.z = (unsigned)f2bf(y.x) | ((unsigned)f2bf(y.y) << 16);
        w.w = (unsigned)f2bf(y.z) | ((unsigned)f2bf(y.w) << 16);
        int byte = e * 128 + q * 16;
        byte ^= (e & 7) << 4;                       // st-style XOR swizzle
        *(uint4*)((char*)(&As[buf][0]) + byte) = w;
    };

    // ---- stage K-step 0 (k in [0,64) -> src table) ----
    {
        const float* p0 = table + (size_t)sIdx[e0] * DFEAT + q * 8;
        const float* p1 = table + (size_t)sIdx[e1] * DFEAT + q * 8;
        float4 a0 = *(const float4*)p0, a1 = *(const float4*)(p0 + 4);
        float4 c0 = *(const float4*)p1, c1 = *(const float4*)(p1 + 4);
        pack_write(0, e0, a0, a1);
        pack_write(0, e1, c0, c1);
    }
    __syncthreads();

    f32x4 acc[4][4];
#pragma unroll
    for (int i = 0; i < 4; i++)
#pragma unroll
        for (int j = 0; j < 4; j++)
            acc[i][j] = (f32x4){0.f, 0.f, 0.f, 0.f};

    for (int s = 0; s < 8; s++) {
        // issue next tile's gather loads early (hide L2/L3 latency under MFMA)
        float4 a0, a1, c0, c1;
        if (s < 7) {
            int sn = s + 1;
            const int* idxA = (sn < 4) ? sIdx : dIdx;
            int cb = (sn & 3) * 64 + q * 8;
            const float* p0 = table + (size_t)idxA[e0] * DFEAT + cb;
            const float* p1 = table + (size_t)idxA[e1] * DFEAT + cb;
            a0 = *(const float4*)p0; a1 = *(const float4*)(p0 + 4);
            c0 = *(const float4*)p1; c1 = *(const float4*)(p1 + 4);
        }

        const int cur = s & 1;
        const char* Abase = (const char*)(&As[cur][0]);
#pragma unroll
        for (int h = 0; h < 2; h++) {
            short8 af[4], bf[4];
#pragma unroll
            for (int i = 0; i < 4; i++) {
                int row = i * 16 + (l & 15);
                int byte = row * 128 + h * 64 + ((l >> 4) << 4);
                byte ^= (l & 7) << 4;               // row&7 == l&7
                af[i] = *(const short8*)(Abase + byte);
            }
#pragma unroll
            for (int j = 0; j < 4; j++) {
                int col = wv * 64 + j * 16 + (l & 15);
                int koff = s * 64 + h * 32 + ((l >> 4) << 3);
                bf[j] = *(const short8*)(w1t + col * KDIM + koff);
            }
#pragma unroll
            for (int i = 0; i < 4; i++)
#pragma unroll
                for (int j = 0; j < 4; j++)
                    acc[i][j] = __builtin_amdgcn_mfma_f32_16x16x32_bf16(af[i], bf[j], acc[i][j], 0, 0, 0);
        }

        if (s < 7) {
            pack_write((s + 1) & 1, e0, a0, a1);
            pack_write((s + 1) & 1, e1, c0, c1);
        }
        __syncthreads();
    }

    // ---- fused epilogue: relu(acc + b1) dot W2, reduce over cols ----
    float part[16];
#pragma unroll
    for (int i = 0; i < 4; i++) {
#pragma unroll
        for (int r = 0; r < 4; r++) {
            float p = 0.f;
#pragma unroll
            for (int j = 0; j < 4; j++) {
                float hv = acc[i][j][r] + b1v[j];
                hv = fmaxf(hv, 0.f);
                p = fmaf(hv, w2v[j], p);
            }
            // reduce across the 16 lanes (l&15) holding this row's cols
#pragma unroll
            for (int mk = 1; mk < 16; mk <<= 1) p += __shfl_xor(p, mk, 64);
            part[i * 4 + r] = p;
        }
    }
    if ((l & 15) == 0) {
        int g = l >> 4;
#pragma unroll
        for (int i = 0; i < 4; i++)
#pragma unroll
            for (int r = 0; r < 4; r++)
                wpart[wv][i * 16 + g * 4 + r] = part[i * 4 + r];
    }
    __syncthreads();

    if (tid < 64) {
        float x = wpart[0][tid] + wpart[1][tid] + wpart[2][tid] + wpart[3][tid] + b2[0];
        float sg = 1.0f / (1.0f + __expf(-x));
        out[(size_t)m0 + tid] = sg;
        out[(size_t)(2 * E_EDGES) + m0 + tid] = (m0 < E_EDGES) ? 1.0f : 0.0f;
    }
}

extern "C" void kernel_launch(void* const* d_in, const int* in_sizes, int n_in,
                              void* d_out, int out_size, void* d_ws, size_t ws_size,
                              hipStream_t stream) {
    const float* table = (const float*)d_in[0];
    const int* ps = (const int*)d_in[1];
    const int* pd = (const int*)d_in[2];
    const int* ns = (const int*)d_in[3];
    const int* nd = (const int*)d_in[4];
    const float* W1 = (const float*)d_in[5];
    const float* b1 = (const float*)d_in[6];
    const float* W2 = (const float*)d_in[7];
    const float* b2 = (const float*)d_in[8];
    unsigned short* w1t = (unsigned short*)d_ws;   // 256 KB
    float* out = (float*)d_out;

    hipLaunchKernelGGL(prep_w1t_kernel, dim3(512), dim3(256), 0, stream, W1, w1t);
    hipLaunchKernelGGL(linkpred_kernel, dim3(8192), dim3(256), 0, stream,
                       table, ps, pd, ns, nd, b1, W2, b2, w1t, out);
}